// Round 15
// baseline (113.075 us; speedup 1.0000x reference)
//
#include <hip/hip_runtime.h>
#include <stdint.h>

// ProbSparse attention (Informer): B=4, L=2048, H=8, D=64, factor=5 -> U_part=u=40.
// out = broadcast mean(V) except top-40 rows per (b,h) get softmax(Q K^T/8) V.
// Row selection is bit-exact jax.random.randint(key(42),(2048,40),0,2048)
// under jax_threefry_partitionable=True (verified passing).
//
// R14 post-mortem: half-split fixed L2 residency (FETCH 58->24.6MB) but 2x wave
// count cost more than it saved -> k_M is NOT L3-bound. Real invariant: the old
// fragment map read 64 x 16B at stride 32B per instruction (~32 line-requests).
// R15: contiguous 1KB-per-instruction loads (1 segment) + DPP rotation-reduce
// (row_ror 8/4/2/1, pure VALU, no LDS pipe). k_topk reverted to direct-M.

static constexpr int Bc = 4, Lc = 2048, Hc = 8, Dc = 64, NUc = 40;
static constexpr int NCH = 32, CHK = 64;  // key chunks for attention
static constexpr int UT = 10;             // queries per wave (4 waves = 40 u)

struct TF2 { uint32_t a, b; };

__host__ __device__ constexpr uint32_t rotl32c(uint32_t x, int r) {
    return (x << r) | (x >> (32 - r));
}

// Threefry-2x32, 20 rounds (jax._src.prng.threefry2x32), constexpr-foldable.
__host__ __device__ constexpr TF2 tf2x32c(uint32_t k0, uint32_t k1, uint32_t x0, uint32_t x1) {
    uint32_t ks[3] = {k0, k1, k0 ^ k1 ^ 0x1BD11BDAu};
    const int R0[4] = {13, 15, 26, 6};
    const int R1[4] = {17, 29, 16, 24};
    x0 += ks[0];
    x1 += ks[1];
    for (int i = 0; i < 5; ++i) {
        const int* R = (i & 1) ? R1 : R0;
        for (int j = 0; j < 4; ++j) {
            x0 += x1;
            x1 = rotl32c(x1, R[j]);
            x1 ^= x0;
        }
        x0 += ks[(i + 1) % 3];
        x1 += ks[(i + 2) % 3] + (uint32_t)(i + 1);
    }
    return TF2{x0, x1};
}

// DPP move: lane gets value from lane rotated within its row of 16.
// row_ror:N dpp_ctrl = 0x120|N. bound_ctrl=true, full masks (all lanes active).
template <int CTRL>
__device__ __forceinline__ float dpp_rot(float v) {
    return __int_as_float(
        __builtin_amdgcn_update_dpp(0, __float_as_int(v), CTRL, 0xf, 0xf, true));
}
// Full 16-lane reduce via rotations (valid for sum and max; all lanes get result).
__device__ __forceinline__ float red16_sum(float v) {
    v += dpp_rot<0x128>(v);  // ror 8
    v += dpp_rot<0x124>(v);  // ror 4
    v += dpp_rot<0x122>(v);  // ror 2
    v += dpp_rot<0x121>(v);  // ror 1
    return v;
}

// ---------------- k_M: sampled sparsity measure, all 8 heads per wave -----------
// Wave per (b,q). Contiguous fragment map: instr0 = bytes [0,1KB) of the 2KB row
// (heads 0-3, 16 lanes/head), instr1 = [1KB,2KB) (heads 4-7). 1 segment/instr.
// Per-sample head-dots via DPP 16-lane rotation-reduce (VALU pipe, no LDS ops).
__global__ __launch_bounds__(256, 4) void k_M(const float* __restrict__ Q,
                                              const float* __restrict__ K,
                                              float* __restrict__ M,
                                              float* __restrict__ vm) {
    constexpr TF2 K2 = tf2x32c(0u, 42u, 0u, 1u);  // second key of split(key(42))
    int lane = threadIdx.x & 63;
    int w = threadIdx.x >> 6;
    int blk = blockIdx.x;           // 2048 blocks
    if (blk < 8) vm[blk * 256 + threadIdx.x] = 0.f;
    int xcd = blk & 7;              // XCD owns half the q's of one b
    int local = blk >> 3;           // 0..255
    int b = xcd >> 1;
    int q = (xcd & 1) * 1024 + local * 4 + w;
    int g = lane >> 4;              // head group: heads g (lo) and 4+g (hi)
    int myidx = 0;
    if (lane < 40) {
        TF2 r = tf2x32c(K2.a, K2.b, 0u, (uint32_t)(q * 40 + lane));
        myidx = (int)((r.a ^ r.b) & 2047u);
    }

    const float4* Q4 = reinterpret_cast<const float4*>(Q);
    const float4* K4 = reinterpret_cast<const float4*>(K);
    size_t qb = (size_t)(b * Lc + q) * 128;  // float4 slots per (b,l) row
    float4 qv0 = Q4[qb + lane];       // floats [4*lane ..): heads 0-3 slice
    float4 qv1 = Q4[qb + 64 + lane];  // floats [256+4*lane ..): heads 4-7 slice

    float mx0 = -INFINITY, sm0 = 0.f, mx1 = -INFINITY, sm1 = 0.f;
#pragma unroll
    for (int i = 0; i < 5; ++i) {
        float p0[8], p1[8];
#pragma unroll
        for (int j = 0; j < 8; ++j) {
            int kk = __shfl(myidx, i * 8 + j, 64);  // wave-uniform -> SGPR
            size_t rb = (size_t)(b * Lc + kk) * 128;
            float4 kv0 = K4[rb + lane];        // contiguous 1KB per instruction
            float4 kv1 = K4[rb + 64 + lane];   // contiguous 1KB per instruction
            p0[j] = qv0.x * kv0.x + qv0.y * kv0.y + qv0.z * kv0.z + qv0.w * kv0.w;
            p1[j] = qv1.x * kv1.x + qv1.y * kv1.y + qv1.z * kv1.z + qv1.w * kv1.w;
        }
#pragma unroll
        for (int j = 0; j < 8; ++j) {
            float d0 = red16_sum(p0[j]);  // head g dot (all 16 lanes)
            float d1 = red16_sum(p1[j]);  // head 4+g dot
            mx0 = fmaxf(mx0, d0);
            sm0 += d0;
            mx1 = fmaxf(mx1, d1);
            sm1 += d1;
        }
    }
    if ((lane & 15) == 0) {
        M[(b * 8 + g) * Lc + q] = mx0 - sm0 * (1.0f / 2048.0f);
        M[(b * 8 + 4 + g) * Lc + q] = mx1 - sm1 * (1.0f / 2048.0f);
    }
}

// ---------------- k_topk: radix-select top-40 (set-equivalent to stable top_k) ---
__global__ __launch_bounds__(256) void k_topk(const float* __restrict__ M, int* __restrict__ top,
                                              uint32_t* __restrict__ gmask) {
    __shared__ uint32_t hist[256];
    __shared__ uint32_t sh_bin, sh_need;
    __shared__ int sel[NUc];
    __shared__ int tie[128];
    __shared__ uint32_t selCnt, tieCnt;
    int bh = blockIdx.x;
    int t = threadIdx.x;
    uint32_t uk[8];
#pragma unroll
    for (int i = 0; i < 8; ++i) {
        uint32_t s = __float_as_uint(M[bh * Lc + i * 256 + t]);
        uk[i] = (s & 0x80000000u) ? ~s : (s | 0x80000000u);  // monotonic key
    }
    uint32_t prefix = 0, need = NUc;
    for (int pass = 0; pass < 4; ++pass) {
        int shift = 24 - 8 * pass;
        hist[t] = 0;
        __syncthreads();
#pragma unroll
        for (int i = 0; i < 8; ++i) {
            bool ok = (pass == 0) || ((uk[i] >> (shift + 8)) == prefix);
            if (ok) atomicAdd(&hist[(uk[i] >> shift) & 255u], 1u);
        }
        __syncthreads();
        if (t < 64) {  // single-wave suffix scan: lane l covers bins 4l..4l+3
            uint32_t c0 = hist[4 * t], c1 = hist[4 * t + 1];
            uint32_t c2 = hist[4 * t + 2], c3 = hist[4 * t + 3];
            uint32_t s = c0 + c1 + c2 + c3;
            uint32_t suf = s;
#pragma unroll
            for (int m = 1; m < 64; m <<= 1) {
                uint32_t o = __shfl_down(suf, m, 64);
                if (t + m < 64) suf += o;
            }
            uint32_t above = suf - s;
            if (suf >= need && above < need) {  // crossing lane
                uint32_t rem = need - above;
                uint32_t bsel, cnt;
                if (c3 >= rem) { bsel = 4 * t + 3; cnt = rem; }
                else if (c3 + c2 >= rem) { bsel = 4 * t + 2; cnt = rem - c3; }
                else if (c3 + c2 + c1 >= rem) { bsel = 4 * t + 1; cnt = rem - c3 - c2; }
                else { bsel = 4 * t; cnt = rem - c3 - c2 - c1; }
                sh_bin = bsel;
                sh_need = cnt;
            }
        }
        __syncthreads();
        prefix = (pass == 0) ? sh_bin : ((prefix << 8) | sh_bin);
        need = sh_need;
        __syncthreads();
    }
    const uint32_t T = prefix;
    if (t == 0) { selCnt = 0; tieCnt = 0; }
    __syncthreads();
#pragma unroll
    for (int i = 0; i < 8; ++i) {
        int idx = i * 256 + t;
        if (uk[i] > T) {
            uint32_t slot = atomicAdd(&selCnt, 1u);
            if (slot < NUc) sel[slot] = idx;
        } else if (uk[i] == T) {
            uint32_t slot = atomicAdd(&tieCnt, 1u);
            if (slot < 128) tie[slot] = idx;
        }
    }
    __syncthreads();
    if (t == 0) {  // take `need` smallest tie indices (stable top-k semantics)
        int n = (int)tieCnt;
        if (n > 128) n = 128;
        for (int a = 1; a < n; ++a) {
            int key = tie[a], c = a - 1;
            while (c >= 0 && tie[c] > key) { tie[c + 1] = tie[c]; --c; }
            tie[c + 1] = key;
        }
        uint32_t base = selCnt;
        for (uint32_t j = 0; j < need && base + j < NUc; ++j) sel[base + j] = tie[j];
    }
    __syncthreads();
    if (t < NUc) top[bh * NUc + t] = sel[t];
    if (t < 64) {
        uint32_t word = 0;
#pragma unroll
        for (int j = 0; j < NUc; ++j) {
            int s = sel[j];
            if ((s >> 5) == t) word |= 1u << (s & 31);
        }
        gmask[bh * 64 + t] = word;
    }
}

// ---------------- attention partials: 256-thread block = (bh, chunk) -------------
__global__ __launch_bounds__(256, 4) void k_attn_part(const float* __restrict__ Q,
                                                      const float* __restrict__ K,
                                                      const float* __restrict__ V,
                                                      const int* __restrict__ top,
                                                      float* __restrict__ wsO,
                                                      float* __restrict__ wsm,
                                                      float* __restrict__ wsl,
                                                      float* __restrict__ vm) {
    __shared__ float Qs[40][64];     // 10.25 KB
    __shared__ float Ks[64][68];     // 17.4 KB (stride 68: conflict-free b128 reads)
    __shared__ float pT[4][64][12];  // 12.3 KB
    __shared__ int tqs[40];
    int blk = blockIdx.x;            // xcd-affine: 8 XCD x 4 bh x 32 chunk
    int xcd = blk & 7, local = blk >> 3;
    int bh = xcd * 4 + (local >> 5);
    int chunk = local & 31;
    int b = bh >> 3, h = bh & 7;
    int t = threadIdx.x, w = t >> 6, lane = t & 63;

    if (t < 40) tqs[t] = top[bh * NUc + t];
    __syncthreads();
    for (int i = t; i < 40 * 64; i += 256) {
        int u = i >> 6, d = i & 63;
        Qs[u][d] = Q[(((size_t)(b * Lc + tqs[u])) * Hc + h) * Dc + d];
    }
    const float* Kbase = K + (((size_t)(b * Lc + chunk * CHK)) * Hc + h) * Dc;
    for (int f = t; f < 1024; f += 256) {
        int r = f >> 4, c = f & 15;
        *reinterpret_cast<float4*>(&Ks[r][c * 4]) =
            *reinterpret_cast<const float4*>(Kbase + (size_t)r * 512 + c * 4);
    }
    __syncthreads();

    float acc[UT];
#pragma unroll
    for (int u = 0; u < UT; ++u) acc[u] = 0.f;
#pragma unroll
    for (int i = 0; i < 16; ++i) {
        float4 kv = *reinterpret_cast<const float4*>(&Ks[lane][i * 4]);
#pragma unroll
        for (int u = 0; u < UT; ++u) {
            float4 qv = *reinterpret_cast<const float4*>(&Qs[w * UT + u][i * 4]);
            acc[u] += qv.x * kv.x + qv.y * kv.y + qv.z * kv.z + qv.w * kv.w;
        }
    }
#pragma unroll
    for (int u = 0; u < UT; ++u) acc[u] *= 0.125f;
    float mr[UT];
#pragma unroll
    for (int u = 0; u < UT; ++u) {
        float v = acc[u];
#pragma unroll
        for (int m = 1; m < 64; m <<= 1) v = fmaxf(v, __shfl_xor(v, m, 64));
        mr[u] = v;
    }
    float pr[UT];
#pragma unroll
    for (int u = 0; u < UT; ++u) {
        pr[u] = __expf(acc[u] - mr[u]);
        pT[w][lane][u] = pr[u];
    }
    float sr[UT];
#pragma unroll
    for (int u = 0; u < UT; ++u) {
        float v = pr[u];
#pragma unroll
        for (int m = 1; m < 64; m <<= 1) v += __shfl_xor(v, m, 64);
        sr[u] = v;
    }
    int sbase = (bh * NCH + chunk) * NUc + w * UT;
#pragma unroll
    for (int u = 0; u < UT; ++u) {
        if (lane == u) {
            wsm[sbase + u] = mr[u];
            wsl[sbase + u] = sr[u];
        }
    }
#pragma unroll
    for (int u = 0; u < UT; ++u) acc[u] = 0.f;
    float vs = 0.f;
    const float* Vbh = V + ((size_t)b * Lc * Hc + h) * Dc;
#pragma unroll 8
    for (int k = 0; k < 64; ++k) {
        float vv = Vbh[(size_t)(chunk * CHK + k) * 512 + lane];
        vs += vv;
        float4 pa = *reinterpret_cast<const float4*>(&pT[w][k][0]);
        float4 pb = *reinterpret_cast<const float4*>(&pT[w][k][4]);
        float2 pc = *reinterpret_cast<const float2*>(&pT[w][k][8]);
        acc[0] += pa.x * vv; acc[1] += pa.y * vv; acc[2] += pa.z * vv; acc[3] += pa.w * vv;
        acc[4] += pb.x * vv; acc[5] += pb.y * vv; acc[6] += pb.z * vv; acc[7] += pb.w * vv;
        acc[8] += pc.x * vv; acc[9] += pc.y * vv;
    }
    if (w == 0) atomicAdd(&vm[bh * 64 + lane], vs * (1.0f / 2048.0f));
    size_t obase = (size_t)(bh * NCH + chunk) * 2560 + (size_t)(w * UT) * 64;
#pragma unroll
    for (int u = 0; u < UT; ++u) wsO[obase + u * 64 + lane] = acc[u];
}

// ---------------- Path A: fused output with inline 32-chunk combine --------------
__global__ void k_out_inl(const float* __restrict__ wsO, const float* __restrict__ wsm,
                          const float* __restrict__ wsl, const float* __restrict__ vm,
                          const int* __restrict__ top, const uint32_t* __restrict__ gmask,
                          float* __restrict__ out) {
    int o4 = blockIdx.x * blockDim.x + threadIdx.x;  // over 1M float4
    if (o4 >= Bc * Lc * Hc * (Dc / 4)) return;
    int dq = o4 & 15;
    int h = (o4 >> 4) & 7;
    int bl = o4 >> 7;
    int b = bl >> 11, l = bl & 2047;
    int bh = b * 8 + h;
    float4 v;
    uint32_t wmask = gmask[bh * 64 + (l >> 5)];
    if ((wmask >> (l & 31)) & 1u) {
        int u = 0;
#pragma unroll
        for (int j = 0; j < NUc; ++j)
            if (top[bh * NUc + j] == l) u = j;
        float cf[NCH];
        float m = -INFINITY;
#pragma unroll
        for (int c = 0; c < NCH; ++c) {
            cf[c] = wsm[(bh * NCH + c) * NUc + u];
            m = fmaxf(m, cf[c]);
        }
        float L = 0.f;
#pragma unroll
        for (int c = 0; c < NCH; ++c) {
            float e = __expf(cf[c] - m);
            L += wsl[(bh * NCH + c) * NUc + u] * e;
            cf[c] = e;
        }
        const float4* W4 = reinterpret_cast<const float4*>(wsO);
        float4 a = make_float4(0.f, 0.f, 0.f, 0.f);
#pragma unroll
        for (int c = 0; c < NCH; ++c) {
            float4 o = W4[(size_t)(bh * NCH + c) * 640 + u * 16 + dq];
            a.x += o.x * cf[c]; a.y += o.y * cf[c]; a.z += o.z * cf[c]; a.w += o.w * cf[c];
        }
        float inv = 1.0f / L;
        v = make_float4(a.x * inv, a.y * inv, a.z * inv, a.w * inv);
    } else {
        v = reinterpret_cast<const float4*>(vm)[bh * 16 + dq];
    }
    reinterpret_cast<float4*>(out)[o4] = v;
}

// ---------------- Path B fallback: comb (stats only) + staged out ----------------
__global__ __launch_bounds__(256) void k_comb(const float* __restrict__ wsO,
                                              const float* __restrict__ wsm,
                                              const float* __restrict__ wsl,
                                              float* __restrict__ stage) {
    __shared__ float cm[NCH][5], cl[NCH][5], cf[NCH][5];
    int blk = blockIdx.x;  // bh*8 + ut
    int ut = blk & 7, bh = blk >> 3;
    int t = threadIdx.x;
    for (int i = t; i < NCH * 5; i += 256) {
        int c = i / 5, j = i % 5;
        cm[c][j] = wsm[(bh * NCH + c) * NUc + ut * 5 + j];
        cl[c][j] = wsl[(bh * NCH + c) * NUc + ut * 5 + j];
    }
    __syncthreads();
    if (t < 5) {
        float m = -INFINITY;
#pragma unroll
        for (int c = 0; c < NCH; ++c) m = fmaxf(m, cm[c][t]);
        float L = 0.f;
#pragma unroll
        for (int c = 0; c < NCH; ++c) {
            float f = __expf(cm[c][t] - m);
            L += cl[c][t] * f;
            cf[c][t] = f;
        }
        float inv = 1.0f / L;
#pragma unroll
        for (int c = 0; c < NCH; ++c) cf[c][t] *= inv;
    }
    __syncthreads();
    for (int i = t; i < 5 * 64; i += 256) {
        int j = i >> 6, d = i & 63;
        float val = 0.f;
#pragma unroll
        for (int c = 0; c < NCH; ++c)
            val += wsO[((size_t)(bh * NCH + c)) * 2560 + (ut * 5 + j) * 64 + d] * cf[c][j];
        stage[(size_t)bh * 2560 + (ut * 5 + j) * 64 + d] = val;
    }
}

__global__ void k_out(const float* __restrict__ stage, const float* __restrict__ vm,
                      const int* __restrict__ top, const uint32_t* __restrict__ gmask,
                      float* __restrict__ out) {
    int o4 = blockIdx.x * blockDim.x + threadIdx.x;
    if (o4 >= Bc * Lc * Hc * (Dc / 4)) return;
    int dq = o4 & 15;
    int h = (o4 >> 4) & 7;
    int bl = o4 >> 7;
    int b = bl >> 11, l = bl & 2047;
    int bh = b * 8 + h;
    float4 v;
    uint32_t wmask = gmask[bh * 64 + (l >> 5)];
    if ((wmask >> (l & 31)) & 1u) {
        int u = 0;
#pragma unroll
        for (int j = 0; j < NUc; ++j)
            if (top[bh * NUc + j] == l) u = j;
        v = reinterpret_cast<const float4*>(stage)[(bh * NUc + u) * 16 + dq];
    } else {
        v = reinterpret_cast<const float4*>(vm)[bh * 16 + dq];
    }
    reinterpret_cast<float4*>(out)[o4] = v;
}

extern "C" void kernel_launch(void* const* d_in, const int* in_sizes, int n_in,
                              void* d_out, int out_size, void* d_ws, size_t ws_size,
                              hipStream_t stream) {
    (void)in_sizes; (void)n_in; (void)out_size;
    const float* Q = (const float*)d_in[0];
    const float* K = (const float*)d_in[1];
    const float* V = (const float*)d_in[2];
    float* out = (float*)d_out;

    int*      top   = (int*)d_ws;                          // 6.4 KB (pad to 8K)
    float*    vm    = (float*)((char*)d_ws + 8192);        // 8 KB
    uint32_t* gmask = (uint32_t*)((char*)d_ws + 16384);    // 8 KB
    float* M = (float*)((char*)d_out + 11075584);          // 256 KB (high in d_out)

    const bool bigws = ws_size >= 11534336;  // deterministic per-harness

    if (bigws) {
        // Path A: partials in d_ws -> no comb kernel, k_out combines inline.
        float* wsm = (float*)((char*)d_ws + 32768);        // 160 KB
        float* wsl = (float*)((char*)d_ws + 196608);       // 160 KB
        float* wsO = (float*)((char*)d_ws + 393216);       // 10.49 MB
        hipLaunchKernelGGL(k_M, dim3(2048), dim3(256), 0, stream, Q, K, M, vm);
        hipLaunchKernelGGL(k_topk, dim3(Bc * Hc), dim3(256), 0, stream, M, top, gmask);
        hipLaunchKernelGGL(k_attn_part, dim3(1024), dim3(256), 0, stream, Q, K, V, top,
                           wsO, wsm, wsl, vm);
        hipLaunchKernelGGL(k_out_inl, dim3(4096), dim3(256), 0, stream, wsO, wsm, wsl, vm,
                           top, gmask, out);
    } else {
        // Path B: partials in d_out, staged combine (race-free vs out writes).
        float* wsO   = (float*)d_out;                      // 10.49 MB
        float* wsm   = (float*)((char*)d_out + 10485760);  // 160 KB
        float* wsl   = (float*)((char*)d_out + 10649600);  // 160 KB
        float* stage = (float*)((char*)d_ws + 24576);      // 320 KB
        hipLaunchKernelGGL(k_M, dim3(2048), dim3(256), 0, stream, Q, K, M, vm);
        hipLaunchKernelGGL(k_topk, dim3(Bc * Hc), dim3(256), 0, stream, M, top, gmask);
        hipLaunchKernelGGL(k_attn_part, dim3(1024), dim3(256), 0, stream, Q, K, V, top,
                           wsO, wsm, wsl, vm);
        hipLaunchKernelGGL(k_comb, dim3(Bc * Hc * 8), dim3(256), 0, stream, wsO, wsm, wsl,
                           stage);
        hipLaunchKernelGGL(k_out, dim3(4096), dim3(256), 0, stream, stage, vm, top, gmask,
                           out);
    }
}

// Round 16
// 82.623 us; speedup vs baseline: 1.3686x; 1.3686x over previous
//
#include <hip/hip_runtime.h>
#include <stdint.h>

// ProbSparse attention (Informer): B=4, L=2048, H=8, D=64, factor=5 -> U_part=u=40.
// out = broadcast mean(V) except top-40 rows per (b,h) get softmax(Q K^T/8) V.
// Row selection is bit-exact jax.random.randint(key(42),(2048,40),0,2048)
// under jax_threefry_partitionable=True (verified passing).
//
// R15 post-mortem: contiguous-load k_M spilled (WRITE_SIZE 98 MB/dispatch = scratch)
// because the full 40-sample unroll batched 80 float4 loads through p[8] arrays at
// a 64-VGPR budget. R16: same contiguous 1KB-per-instruction map (32 line-requests
// per sample vs R13's 64) + DPP 16-lane reduce, batched 4 samples, outer loop
// pinned (#pragma unroll 1) -> ~60 live VGPRs, no spill.

static constexpr int Bc = 4, Lc = 2048, Hc = 8, Dc = 64, NUc = 40;
static constexpr int NCH = 32, CHK = 64;  // key chunks for attention
static constexpr int UT = 10;             // queries per wave (4 waves = 40 u)

struct TF2 { uint32_t a, b; };

__host__ __device__ constexpr uint32_t rotl32c(uint32_t x, int r) {
    return (x << r) | (x >> (32 - r));
}

// Threefry-2x32, 20 rounds (jax._src.prng.threefry2x32), constexpr-foldable.
__host__ __device__ constexpr TF2 tf2x32c(uint32_t k0, uint32_t k1, uint32_t x0, uint32_t x1) {
    uint32_t ks[3] = {k0, k1, k0 ^ k1 ^ 0x1BD11BDAu};
    const int R0[4] = {13, 15, 26, 6};
    const int R1[4] = {17, 29, 16, 24};
    x0 += ks[0];
    x1 += ks[1];
    for (int i = 0; i < 5; ++i) {
        const int* R = (i & 1) ? R1 : R0;
        for (int j = 0; j < 4; ++j) {
            x0 += x1;
            x1 = rotl32c(x1, R[j]);
            x1 ^= x0;
        }
        x0 += ks[(i + 1) % 3];
        x1 += ks[(i + 2) % 3] + (uint32_t)(i + 1);
    }
    return TF2{x0, x1};
}

// DPP move: lane gets value from lane rotated within its row of 16.
// row_ror:N dpp_ctrl = 0x120|N. bound_ctrl=true, full masks (all lanes active).
template <int CTRL>
__device__ __forceinline__ float dpp_rot(float v) {
    return __int_as_float(
        __builtin_amdgcn_update_dpp(0, __float_as_int(v), CTRL, 0xf, 0xf, true));
}
// Full 16-lane reduce via rotations (all 16 lanes get the sum). HW-verified (R15).
__device__ __forceinline__ float red16_sum(float v) {
    v += dpp_rot<0x128>(v);  // ror 8
    v += dpp_rot<0x124>(v);  // ror 4
    v += dpp_rot<0x122>(v);  // ror 2
    v += dpp_rot<0x121>(v);  // ror 1
    return v;
}

// ---------------- k_M: sampled sparsity measure, all 8 heads per wave -----------
// Wave per (b,q). Contiguous map: load A = bytes [0,1KB) of the 2KB K row (heads
// 0-3, 16 lanes/head), load B = [1KB,2KB) (heads 4-7). 1 segment & 16 lines per
// instruction (R13's interleaved map touched 32 lines twice). Dots via DPP
// 16-lane rotation-reduce (VALU pipe). 4-sample batches to stay spill-free.
__global__ __launch_bounds__(256, 4) void k_M(const float* __restrict__ Q,
                                              const float* __restrict__ K,
                                              float* __restrict__ M,
                                              float* __restrict__ vm) {
    constexpr TF2 K2 = tf2x32c(0u, 42u, 0u, 1u);  // second key of split(key(42))
    int lane = threadIdx.x & 63;
    int w = threadIdx.x >> 6;
    int blk = blockIdx.x;           // 2048 blocks
    if (blk < 8) vm[blk * 256 + threadIdx.x] = 0.f;
    int xcd = blk & 7;              // XCD owns half the q's of one b
    int local = blk >> 3;           // 0..255
    int b = xcd >> 1;
    int q = (xcd & 1) * 1024 + local * 4 + w;
    int g = lane >> 4;              // head group: heads g (lo) and 4+g (hi)
    int myidx = 0;
    if (lane < 40) {
        TF2 r = tf2x32c(K2.a, K2.b, 0u, (uint32_t)(q * 40 + lane));
        myidx = (int)((r.a ^ r.b) & 2047u);
    }

    const float4* Q4 = reinterpret_cast<const float4*>(Q);
    const float4* K4 = reinterpret_cast<const float4*>(K);
    size_t qb = (size_t)(b * Lc + q) * 128;  // float4 slots per (b,l) row
    float4 qv0 = Q4[qb + lane];       // floats [4*lane ..): heads 0-3 slice
    float4 qv1 = Q4[qb + 64 + lane];  // floats [256+4*lane ..): heads 4-7 slice

    float mx0 = -INFINITY, sm0 = 0.f, mx1 = -INFINITY, sm1 = 0.f;
#pragma unroll 1
    for (int i = 0; i < 10; ++i) {   // 10 batches x 4 samples; DO NOT merge (spill)
        float d0[4], d1[4];
#pragma unroll
        for (int j = 0; j < 4; ++j) {
            int kk = __shfl(myidx, i * 4 + j, 64);  // wave-uniform -> SGPR
            size_t rb = (size_t)(b * Lc + kk) * 128;
            float4 kv0 = K4[rb + lane];        // contiguous 1KB, 16 lines
            float4 kv1 = K4[rb + 64 + lane];   // contiguous 1KB, 16 lines
            d0[j] = qv0.x * kv0.x + qv0.y * kv0.y + qv0.z * kv0.z + qv0.w * kv0.w;
            d1[j] = qv1.x * kv1.x + qv1.y * kv1.y + qv1.z * kv1.z + qv1.w * kv1.w;
        }
#pragma unroll
        for (int j = 0; j < 4; ++j) {
            float t0 = red16_sum(d0[j]);  // head g dot (all 16 lanes)
            float t1 = red16_sum(d1[j]);  // head 4+g dot
            mx0 = fmaxf(mx0, t0);
            sm0 += t0;
            mx1 = fmaxf(mx1, t1);
            sm1 += t1;
        }
    }
    if ((lane & 15) == 0) {
        M[(b * 8 + g) * Lc + q] = mx0 - sm0 * (1.0f / 2048.0f);
        M[(b * 8 + 4 + g) * Lc + q] = mx1 - sm1 * (1.0f / 2048.0f);
    }
}

// ---------------- k_topk: radix-select top-40 (set-equivalent to stable top_k) ---
__global__ __launch_bounds__(256) void k_topk(const float* __restrict__ M, int* __restrict__ top,
                                              uint32_t* __restrict__ gmask) {
    __shared__ uint32_t hist[256];
    __shared__ uint32_t sh_bin, sh_need;
    __shared__ int sel[NUc];
    __shared__ int tie[128];
    __shared__ uint32_t selCnt, tieCnt;
    int bh = blockIdx.x;
    int t = threadIdx.x;
    uint32_t uk[8];
#pragma unroll
    for (int i = 0; i < 8; ++i) {
        uint32_t s = __float_as_uint(M[bh * Lc + i * 256 + t]);
        uk[i] = (s & 0x80000000u) ? ~s : (s | 0x80000000u);  // monotonic key
    }
    uint32_t prefix = 0, need = NUc;
    for (int pass = 0; pass < 4; ++pass) {
        int shift = 24 - 8 * pass;
        hist[t] = 0;
        __syncthreads();
#pragma unroll
        for (int i = 0; i < 8; ++i) {
            bool ok = (pass == 0) || ((uk[i] >> (shift + 8)) == prefix);
            if (ok) atomicAdd(&hist[(uk[i] >> shift) & 255u], 1u);
        }
        __syncthreads();
        if (t < 64) {  // single-wave suffix scan: lane l covers bins 4l..4l+3
            uint32_t c0 = hist[4 * t], c1 = hist[4 * t + 1];
            uint32_t c2 = hist[4 * t + 2], c3 = hist[4 * t + 3];
            uint32_t s = c0 + c1 + c2 + c3;
            uint32_t suf = s;
#pragma unroll
            for (int m = 1; m < 64; m <<= 1) {
                uint32_t o = __shfl_down(suf, m, 64);
                if (t + m < 64) suf += o;
            }
            uint32_t above = suf - s;
            if (suf >= need && above < need) {  // crossing lane
                uint32_t rem = need - above;
                uint32_t bsel, cnt;
                if (c3 >= rem) { bsel = 4 * t + 3; cnt = rem; }
                else if (c3 + c2 >= rem) { bsel = 4 * t + 2; cnt = rem - c3; }
                else if (c3 + c2 + c1 >= rem) { bsel = 4 * t + 1; cnt = rem - c3 - c2; }
                else { bsel = 4 * t; cnt = rem - c3 - c2 - c1; }
                sh_bin = bsel;
                sh_need = cnt;
            }
        }
        __syncthreads();
        prefix = (pass == 0) ? sh_bin : ((prefix << 8) | sh_bin);
        need = sh_need;
        __syncthreads();
    }
    const uint32_t T = prefix;
    if (t == 0) { selCnt = 0; tieCnt = 0; }
    __syncthreads();
#pragma unroll
    for (int i = 0; i < 8; ++i) {
        int idx = i * 256 + t;
        if (uk[i] > T) {
            uint32_t slot = atomicAdd(&selCnt, 1u);
            if (slot < NUc) sel[slot] = idx;
        } else if (uk[i] == T) {
            uint32_t slot = atomicAdd(&tieCnt, 1u);
            if (slot < 128) tie[slot] = idx;
        }
    }
    __syncthreads();
    if (t == 0) {  // take `need` smallest tie indices (stable top-k semantics)
        int n = (int)tieCnt;
        if (n > 128) n = 128;
        for (int a = 1; a < n; ++a) {
            int key = tie[a], c = a - 1;
            while (c >= 0 && tie[c] > key) { tie[c + 1] = tie[c]; --c; }
            tie[c + 1] = key;
        }
        uint32_t base = selCnt;
        for (uint32_t j = 0; j < need && base + j < NUc; ++j) sel[base + j] = tie[j];
    }
    __syncthreads();
    if (t < NUc) top[bh * NUc + t] = sel[t];
    if (t < 64) {
        uint32_t word = 0;
#pragma unroll
        for (int j = 0; j < NUc; ++j) {
            int s = sel[j];
            if ((s >> 5) == t) word |= 1u << (s & 31);
        }
        gmask[bh * 64 + t] = word;
    }
}

// ---------------- attention partials: 256-thread block = (bh, chunk) -------------
__global__ __launch_bounds__(256, 4) void k_attn_part(const float* __restrict__ Q,
                                                      const float* __restrict__ K,
                                                      const float* __restrict__ V,
                                                      const int* __restrict__ top,
                                                      float* __restrict__ wsO,
                                                      float* __restrict__ wsm,
                                                      float* __restrict__ wsl,
                                                      float* __restrict__ vm) {
    __shared__ float Qs[40][64];     // 10.25 KB
    __shared__ float Ks[64][68];     // 17.4 KB (stride 68: conflict-free b128 reads)
    __shared__ float pT[4][64][12];  // 12.3 KB
    __shared__ int tqs[40];
    int blk = blockIdx.x;            // xcd-affine: 8 XCD x 4 bh x 32 chunk
    int xcd = blk & 7, local = blk >> 3;
    int bh = xcd * 4 + (local >> 5);
    int chunk = local & 31;
    int b = bh >> 3, h = bh & 7;
    int t = threadIdx.x, w = t >> 6, lane = t & 63;

    if (t < 40) tqs[t] = top[bh * NUc + t];
    __syncthreads();
    for (int i = t; i < 40 * 64; i += 256) {
        int u = i >> 6, d = i & 63;
        Qs[u][d] = Q[(((size_t)(b * Lc + tqs[u])) * Hc + h) * Dc + d];
    }
    const float* Kbase = K + (((size_t)(b * Lc + chunk * CHK)) * Hc + h) * Dc;
    for (int f = t; f < 1024; f += 256) {
        int r = f >> 4, c = f & 15;
        *reinterpret_cast<float4*>(&Ks[r][c * 4]) =
            *reinterpret_cast<const float4*>(Kbase + (size_t)r * 512 + c * 4);
    }
    __syncthreads();

    float acc[UT];
#pragma unroll
    for (int u = 0; u < UT; ++u) acc[u] = 0.f;
#pragma unroll
    for (int i = 0; i < 16; ++i) {
        float4 kv = *reinterpret_cast<const float4*>(&Ks[lane][i * 4]);
#pragma unroll
        for (int u = 0; u < UT; ++u) {
            float4 qv = *reinterpret_cast<const float4*>(&Qs[w * UT + u][i * 4]);
            acc[u] += qv.x * kv.x + qv.y * kv.y + qv.z * kv.z + qv.w * kv.w;
        }
    }
#pragma unroll
    for (int u = 0; u < UT; ++u) acc[u] *= 0.125f;
    float mr[UT];
#pragma unroll
    for (int u = 0; u < UT; ++u) {
        float v = acc[u];
#pragma unroll
        for (int m = 1; m < 64; m <<= 1) v = fmaxf(v, __shfl_xor(v, m, 64));
        mr[u] = v;
    }
    float pr[UT];
#pragma unroll
    for (int u = 0; u < UT; ++u) {
        pr[u] = __expf(acc[u] - mr[u]);
        pT[w][lane][u] = pr[u];
    }
    float sr[UT];
#pragma unroll
    for (int u = 0; u < UT; ++u) {
        float v = pr[u];
#pragma unroll
        for (int m = 1; m < 64; m <<= 1) v += __shfl_xor(v, m, 64);
        sr[u] = v;
    }
    int sbase = (bh * NCH + chunk) * NUc + w * UT;
#pragma unroll
    for (int u = 0; u < UT; ++u) {
        if (lane == u) {
            wsm[sbase + u] = mr[u];
            wsl[sbase + u] = sr[u];
        }
    }
#pragma unroll
    for (int u = 0; u < UT; ++u) acc[u] = 0.f;
    float vs = 0.f;
    const float* Vbh = V + ((size_t)b * Lc * Hc + h) * Dc;
#pragma unroll 8
    for (int k = 0; k < 64; ++k) {
        float vv = Vbh[(size_t)(chunk * CHK + k) * 512 + lane];
        vs += vv;
        float4 pa = *reinterpret_cast<const float4*>(&pT[w][k][0]);
        float4 pb = *reinterpret_cast<const float4*>(&pT[w][k][4]);
        float2 pc = *reinterpret_cast<const float2*>(&pT[w][k][8]);
        acc[0] += pa.x * vv; acc[1] += pa.y * vv; acc[2] += pa.z * vv; acc[3] += pa.w * vv;
        acc[4] += pb.x * vv; acc[5] += pb.y * vv; acc[6] += pb.z * vv; acc[7] += pb.w * vv;
        acc[8] += pc.x * vv; acc[9] += pc.y * vv;
    }
    if (w == 0) atomicAdd(&vm[bh * 64 + lane], vs * (1.0f / 2048.0f));
    size_t obase = (size_t)(bh * NCH + chunk) * 2560 + (size_t)(w * UT) * 64;
#pragma unroll
    for (int u = 0; u < UT; ++u) wsO[obase + u * 64 + lane] = acc[u];
}

// ---------------- Path A: fused output with inline 32-chunk combine --------------
__global__ void k_out_inl(const float* __restrict__ wsO, const float* __restrict__ wsm,
                          const float* __restrict__ wsl, const float* __restrict__ vm,
                          const int* __restrict__ top, const uint32_t* __restrict__ gmask,
                          float* __restrict__ out) {
    int o4 = blockIdx.x * blockDim.x + threadIdx.x;  // over 1M float4
    if (o4 >= Bc * Lc * Hc * (Dc / 4)) return;
    int dq = o4 & 15;
    int h = (o4 >> 4) & 7;
    int bl = o4 >> 7;
    int b = bl >> 11, l = bl & 2047;
    int bh = b * 8 + h;
    float4 v;
    uint32_t wmask = gmask[bh * 64 + (l >> 5)];
    if ((wmask >> (l & 31)) & 1u) {
        int u = 0;
#pragma unroll
        for (int j = 0; j < NUc; ++j)
            if (top[bh * NUc + j] == l) u = j;
        float cf[NCH];
        float m = -INFINITY;
#pragma unroll
        for (int c = 0; c < NCH; ++c) {
            cf[c] = wsm[(bh * NCH + c) * NUc + u];
            m = fmaxf(m, cf[c]);
        }
        float L = 0.f;
#pragma unroll
        for (int c = 0; c < NCH; ++c) {
            float e = __expf(cf[c] - m);
            L += wsl[(bh * NCH + c) * NUc + u] * e;
            cf[c] = e;
        }
        const float4* W4 = reinterpret_cast<const float4*>(wsO);
        float4 a = make_float4(0.f, 0.f, 0.f, 0.f);
#pragma unroll
        for (int c = 0; c < NCH; ++c) {
            float4 o = W4[(size_t)(bh * NCH + c) * 640 + u * 16 + dq];
            a.x += o.x * cf[c]; a.y += o.y * cf[c]; a.z += o.z * cf[c]; a.w += o.w * cf[c];
        }
        float inv = 1.0f / L;
        v = make_float4(a.x * inv, a.y * inv, a.z * inv, a.w * inv);
    } else {
        v = reinterpret_cast<const float4*>(vm)[bh * 16 + dq];
    }
    reinterpret_cast<float4*>(out)[o4] = v;
}

// ---------------- Path B fallback: comb (stats only) + staged out ----------------
__global__ __launch_bounds__(256) void k_comb(const float* __restrict__ wsO,
                                              const float* __restrict__ wsm,
                                              const float* __restrict__ wsl,
                                              float* __restrict__ stage) {
    __shared__ float cm[NCH][5], cl[NCH][5], cf[NCH][5];
    int blk = blockIdx.x;  // bh*8 + ut
    int ut = blk & 7, bh = blk >> 3;
    int t = threadIdx.x;
    for (int i = t; i < NCH * 5; i += 256) {
        int c = i / 5, j = i % 5;
        cm[c][j] = wsm[(bh * NCH + c) * NUc + ut * 5 + j];
        cl[c][j] = wsl[(bh * NCH + c) * NUc + ut * 5 + j];
    }
    __syncthreads();
    if (t < 5) {
        float m = -INFINITY;
#pragma unroll
        for (int c = 0; c < NCH; ++c) m = fmaxf(m, cm[c][t]);
        float L = 0.f;
#pragma unroll
        for (int c = 0; c < NCH; ++c) {
            float f = __expf(cm[c][t] - m);
            L += cl[c][t] * f;
            cf[c][t] = f;
        }
        float inv = 1.0f / L;
#pragma unroll
        for (int c = 0; c < NCH; ++c) cf[c][t] *= inv;
    }
    __syncthreads();
    for (int i = t; i < 5 * 64; i += 256) {
        int j = i >> 6, d = i & 63;
        float val = 0.f;
#pragma unroll
        for (int c = 0; c < NCH; ++c)
            val += wsO[((size_t)(bh * NCH + c)) * 2560 + (ut * 5 + j) * 64 + d] * cf[c][j];
        stage[(size_t)bh * 2560 + (ut * 5 + j) * 64 + d] = val;
    }
}

__global__ void k_out(const float* __restrict__ stage, const float* __restrict__ vm,
                      const int* __restrict__ top, const uint32_t* __restrict__ gmask,
                      float* __restrict__ out) {
    int o4 = blockIdx.x * blockDim.x + threadIdx.x;
    if (o4 >= Bc * Lc * Hc * (Dc / 4)) return;
    int dq = o4 & 15;
    int h = (o4 >> 4) & 7;
    int bl = o4 >> 7;
    int b = bl >> 11, l = bl & 2047;
    int bh = b * 8 + h;
    float4 v;
    uint32_t wmask = gmask[bh * 64 + (l >> 5)];
    if ((wmask >> (l & 31)) & 1u) {
        int u = 0;
#pragma unroll
        for (int j = 0; j < NUc; ++j)
            if (top[bh * NUc + j] == l) u = j;
        v = reinterpret_cast<const float4*>(stage)[(bh * NUc + u) * 16 + dq];
    } else {
        v = reinterpret_cast<const float4*>(vm)[bh * 16 + dq];
    }
    reinterpret_cast<float4*>(out)[o4] = v;
}

extern "C" void kernel_launch(void* const* d_in, const int* in_sizes, int n_in,
                              void* d_out, int out_size, void* d_ws, size_t ws_size,
                              hipStream_t stream) {
    (void)in_sizes; (void)n_in; (void)out_size;
    const float* Q = (const float*)d_in[0];
    const float* K = (const float*)d_in[1];
    const float* V = (const float*)d_in[2];
    float* out = (float*)d_out;

    int*      top   = (int*)d_ws;                          // 6.4 KB (pad to 8K)
    float*    vm    = (float*)((char*)d_ws + 8192);        // 8 KB
    uint32_t* gmask = (uint32_t*)((char*)d_ws + 16384);    // 8 KB
    float* M = (float*)((char*)d_out + 11075584);          // 256 KB (high in d_out)

    const bool bigws = ws_size >= 11534336;  // deterministic per-harness

    if (bigws) {
        // Path A: partials in d_ws -> no comb kernel, k_out combines inline.
        float* wsm = (float*)((char*)d_ws + 32768);        // 160 KB
        float* wsl = (float*)((char*)d_ws + 196608);       // 160 KB
        float* wsO = (float*)((char*)d_ws + 393216);       // 10.49 MB
        hipLaunchKernelGGL(k_M, dim3(2048), dim3(256), 0, stream, Q, K, M, vm);
        hipLaunchKernelGGL(k_topk, dim3(Bc * Hc), dim3(256), 0, stream, M, top, gmask);
        hipLaunchKernelGGL(k_attn_part, dim3(1024), dim3(256), 0, stream, Q, K, V, top,
                           wsO, wsm, wsl, vm);
        hipLaunchKernelGGL(k_out_inl, dim3(4096), dim3(256), 0, stream, wsO, wsm, wsl, vm,
                           top, gmask, out);
    } else {
        // Path B: partials in d_out, staged combine (race-free vs out writes).
        float* wsO   = (float*)d_out;                      // 10.49 MB
        float* wsm   = (float*)((char*)d_out + 10485760);  // 160 KB
        float* wsl   = (float*)((char*)d_out + 10649600);  // 160 KB
        float* stage = (float*)((char*)d_ws + 24576);      // 320 KB
        hipLaunchKernelGGL(k_M, dim3(2048), dim3(256), 0, stream, Q, K, M, vm);
        hipLaunchKernelGGL(k_topk, dim3(Bc * Hc), dim3(256), 0, stream, M, top, gmask);
        hipLaunchKernelGGL(k_attn_part, dim3(1024), dim3(256), 0, stream, Q, K, V, top,
                           wsO, wsm, wsl, vm);
        hipLaunchKernelGGL(k_comb, dim3(Bc * Hc * 8), dim3(256), 0, stream, wsO, wsm, wsl,
                           stage);
        hipLaunchKernelGGL(k_out, dim3(4096), dim3(256), 0, stream, stage, vm, top, gmask,
                           out);
    }
}